// Round 5
// baseline (130.709 us; speedup 1.0000x reference)
//
#include <hip/hip_runtime.h>
#include <math.h>

#define Bn 4
#define Tn 4096
#define Cn 1024
#define Hn 64

typedef __attribute__((ext_vector_type(8))) short short8;
typedef __attribute__((ext_vector_type(4))) float floatx4;
typedef unsigned short ushort_t;

// 0.125 (H^-0.5) * log2(e): folded into Q so attn uses native exp2
#define QSCALE 0.1803368801111204f

__device__ __forceinline__ ushort_t f2bf(float f) {       // RNE
  union { float f; unsigned u; } v; v.f = f;
  unsigned r = v.u + 0x7FFFu + ((v.u >> 16) & 1u);
  return (ushort_t)(r >> 16);
}
__device__ __forceinline__ ushort_t f2bf_hu(float f) {    // round-half-up (P only)
  union { float f; unsigned u; } v; v.f = f;
  return (ushort_t)((v.u + 0x8000u) >> 16);
}
__device__ __forceinline__ float bf2f(ushort_t h) {
  union { unsigned u; float f; } v; v.u = ((unsigned)h) << 16; return v.f;
}

// ---------------------------------------------------------------------------
// Layouts (lane = (quad=lane>>4, col=lane&15); addresses = base + lane*16B):
//  Qf/Kf[b][s=t/16][half=h/32]: lane holds h = half*32+quad*8+e for t=s*16+col.
//  Vf[b][i=t/64][ht=h/16][kh]: lane reg e holds V[t=i*64+pi2(kh,quad,e)][ht*16+col]
//    with pi2 = 32*kh + 16*(e>>2) + 4*quad + (e&3). Matches the SWAPPED-QK
//    register layout of P (S^T = mfma(K,Q): lane holds keys 16*kt+4*quad+r for
//    q=col), so P feeds PV's A-fragment directly from registers -- no LDS.
//  Wf[m][g=c/32][nt=h/16]: lane holds W[c=g*32+quad*8+e][h=nt*16+col].
// R5 restructure: BOTH big kernels moved from 32-row/2-waves-per-SIMD to
// 16-row blocks, grid 1024, launch_bounds(256,4) -> 16 waves/CU. R2 profile
// showed ~88% issue-idle at Occupancy 19% and three ILP-only rounds were
// flat: this is the latency/occupancy row of the roofline table.
// ---------------------------------------------------------------------------

// W^T -> fragment-major bf16. grid = 96 (m*32+g), 256 threads.
__global__ __launch_bounds__(256) void wf_kernel(
    const float* __restrict__ Wq, const float* __restrict__ Wk,
    const float* __restrict__ Wv, ushort_t* __restrict__ Wf)
{
  __shared__ float ws[32][65];
  const int tid = threadIdx.x;
  const int m = blockIdx.x >> 5;
  const int g = blockIdx.x & 31;
  const float* W = (m == 0) ? Wq : (m == 1) ? Wk : Wv;
  const float4* src = (const float4*)(W + (size_t)g * 32 * Hn);
#pragma unroll
  for (int it = 0; it < 2; ++it) {
    int i4 = it * 256 + tid;
    float4 v = src[i4];
    int c = i4 >> 4, h = (i4 & 15) * 4;
    ws[c][h] = v.x; ws[c][h + 1] = v.y; ws[c][h + 2] = v.z; ws[c][h + 3] = v.w;
  }
  __syncthreads();
  const int nt = tid >> 6, lane = tid & 63;
  const int col = lane & 15, quad = lane >> 4;
  ushort_t t[8];
#pragma unroll
  for (int e = 0; e < 8; ++e) t[e] = f2bf(ws[quad * 8 + e][nt * 16 + col]);
  *(short8*)(Wf + ((size_t)((m * 32 + g) * 4 + nt) * 64 + lane) * 8) = *(short8*)t;
}

// ---------------------------------------------------------------------------
// QKV projection. grid = 1024 x 256; block owns 16 rows (ONE subtile), 4
// waves K-split (256 ch each). LDS 33 KB -> 4 blocks/CU (16 waves/CU).
// x staged per-wave to LDS coalesced (8 loads in flight x2); Wf loaded
// single-buffered per ch (TLP hides L2 latency at 4 waves/SIMD).
// Epilogue: partials to LDS bf16 (STATIC acc indexing), per-wave reduce,
// frag-image staging, coalesced copy-out (V as half-fragments via g&1).
// ---------------------------------------------------------------------------
__global__ __launch_bounds__(256, 4) void qkv_proj_kernel(
    const float* __restrict__ x, const ushort_t* __restrict__ Wf,
    ushort_t* __restrict__ Qf, ushort_t* __restrict__ Kf,
    ushort_t* __restrict__ Vf)
{
  __shared__ __align__(16) char smem[33792];
  ushort_t* xs  = (ushort_t*)smem;              // [4 wv][16 row][264] bf16 (33792 B)
  ushort_t* red = (ushort_t*)smem;              // overlays xs: [12][4][64][4] (24576 B)
  ushort_t* img = (ushort_t*)(smem + 24576);    // Q[1024] K[1024] V[1024] (6144 B)

  const int tid  = threadIdx.x;
  const int wv   = tid >> 6;
  const int lane = tid & 63;
  const int col  = lane & 15;
  const int quad = lane >> 4;
  const int blk  = blockIdx.x;
  const int row0 = blk * 16;

  // ---- stage wave's x slice (16 rows x 256 ch) to LDS, 8 loads in flight ----
#pragma unroll
  for (int hb = 0; hb < 2; ++hb) {
    float4 v[8];
#pragma unroll
    for (int jj = 0; jj < 8; ++jj)
      v[jj] = *(const float4*)(x + (size_t)(row0 + hb * 8 + jj) * Cn + wv * 256 + lane * 4);
#pragma unroll
    for (int jj = 0; jj < 8; ++jj) {
      ushort4 u;
      u.x = f2bf(v[jj].x); u.y = f2bf(v[jj].y); u.z = f2bf(v[jj].z); u.w = f2bf(v[jj].w);
      *(ushort4*)(xs + (wv * 16 + hb * 8 + jj) * 264 + lane * 4) = u;
    }
  }
  // wave reads only its own slice -> no barrier (lgkmcnt orders same-wave LDS)

  floatx4 acc[3][4];
#pragma unroll
  for (int m = 0; m < 3; ++m)
#pragma unroll
    for (int nt = 0; nt < 4; ++nt) {
      acc[m][nt][0] = 0.f; acc[m][nt][1] = 0.f;
      acc[m][nt][2] = 0.f; acc[m][nt][3] = 0.f;
    }

  // ---- K-loop: 8 x 32ch; single-buffer Wf (TLP covers L2 latency) ----
#pragma unroll
  for (int ch = 0; ch < 8; ++ch) {
    const int gg = wv * 8 + ch;                 // global 32-ch chunk
    short8 bf[12];
#pragma unroll
    for (int k = 0; k < 12; ++k) {
      const int m_ = k >> 2, nt_ = k & 3;
      bf[k] = *(const short8*)(Wf + ((size_t)((m_ * 32 + gg) * 4 + nt_) * 64 + lane) * 8);
    }
    short8 af = *(const short8*)(xs + (wv * 16 + col) * 264 + ch * 32 + quad * 8);
#pragma unroll
    for (int k = 0; k < 12; ++k)
      acc[k >> 2][k & 3] = __builtin_amdgcn_mfma_f32_16x16x32_bf16(af, bf[k], acc[k >> 2][k & 3], 0, 0, 0);
  }
  __syncthreads();   // xs reads done everywhere; safe to overlay red

  // ---- dump ALL partials to LDS (static acc indices; lane-contiguous 8B) ----
#pragma unroll
  for (int m = 0; m < 3; ++m)
#pragma unroll
    for (int nt = 0; nt < 4; ++nt) {
      const int p = m * 4 + nt;
      ushort4 u;
      u.x = f2bf(acc[m][nt][0]); u.y = f2bf(acc[m][nt][1]);
      u.z = f2bf(acc[m][nt][2]); u.w = f2bf(acc[m][nt][3]);
      *(ushort4*)&red[((p * 4 + wv) * 64 + lane) * 4] = u;
    }
  __syncthreads();

  // ---- wave wv reduces p in [3wv, 3wv+3) from LDS; writes frag-images ----
#pragma unroll
  for (int pp = 0; pp < 3; ++pp) {
    const int p = wv * 3 + pp;
    ushort4 w0 = *(const ushort4*)&red[((p * 4 + 0) * 64 + lane) * 4];
    ushort4 w1 = *(const ushort4*)&red[((p * 4 + 1) * 64 + lane) * 4];
    ushort4 w2 = *(const ushort4*)&red[((p * 4 + 2) * 64 + lane) * 4];
    ushort4 w3 = *(const ushort4*)&red[((p * 4 + 3) * 64 + lane) * 4];
    float v[4];
    v[0] = (bf2f(w0.x) + bf2f(w1.x)) + (bf2f(w2.x) + bf2f(w3.x));
    v[1] = (bf2f(w0.y) + bf2f(w1.y)) + (bf2f(w2.y) + bf2f(w3.y));
    v[2] = (bf2f(w0.z) + bf2f(w1.z)) + (bf2f(w2.z) + bf2f(w3.z));
    v[3] = (bf2f(w0.w) + bf2f(w1.w)) + (bf2f(w2.w) + bf2f(w3.w));
    const int m = p >> 2, nt = p & 3;
#pragma unroll
    for (int r = 0; r < 4; ++r) {
      const int tlq = quad * 4 + r;
      if (m == 2) {
        // V image: slot (lane = quad*16+col, e-low = r); e-high from g&1 at copy-out
        img[2048 + nt * 256 + (quad * 16 + col) * 4 + r] = f2bf(v[r]);
      } else {
        const int h = nt * 16 + col;
        const int idx = (h >> 5) * 512 + ((h >> 3) & 3) * 128 + tlq * 8 + (h & 7);
        img[m * 1024 + idx] = f2bf(m == 0 ? v[r] * QSCALE : v[r]);
      }
    }
  }
  __syncthreads();

  // ---- coalesced copy-out ----
  {
    const int b = blk >> 8, g = blk & 255;
    const size_t qg = (size_t)(b * 256 + g) * 1024 + tid * 4;
    *(uint2*)(Qf + qg) = *(const uint2*)&img[tid * 4];
    *(uint2*)(Kf + qg) = *(const uint2*)&img[1024 + tid * 4];
    const int ht = tid >> 6;
    const size_t vg = ((size_t)(b * 64 + (g >> 2)) * 8 + ht * 2 + ((g >> 1) & 1)) * 512
                      + (tid & 63) * 8 + (g & 1) * 4;
    *(uint2*)(Vf + vg) = *(const uint2*)&img[2048 + ht * 256 + (tid & 63) * 4];
  }
}

// ---------------------------------------------------------------------------
// Flash attention, causal, max-free softmax. grid = B*256 (16-row q-tiles),
// 4 blocks/CU x 4 waves = 16 waves/CU (2x R2's occupancy). g remap balances
// per-CU work. 4 waves stride 64-key tiles with private (O,l). SWAPPED QK^T
// keeps P entirely in registers (zero LDS in main loop). K/V loaded same-tile,
// single-buffered: TLP (4 waves/SIMD) replaces register ping-pong (R4 lesson:
// deep prefetch at 2 waves/SIMD spilled and regressed).
// ---------------------------------------------------------------------------
__global__ __launch_bounds__(256, 4) void attn_kernel(
    const ushort_t* __restrict__ Qf, const ushort_t* __restrict__ Kf,
    const ushort_t* __restrict__ Vf, float* __restrict__ out)
{
  __shared__ __align__(16) float Om[4][16][68];
  __shared__ __align__(16) float Ml[4][16];

  const int tid  = threadIdx.x;
  const int wv   = tid >> 6;
  const int lane = tid & 63;
  const int col  = lane & 15;
  const int quad = lane >> 4;
  const int b   = blockIdx.x & 3;
  const int idx = blockIdx.x >> 2;                          // 0..255
  const int g   = (idx < 128) ? (255 - 2 * idx) : (2 * (idx - 128));  // balanced remap

  short8 qf[2];
#pragma unroll
  for (int half = 0; half < 2; ++half)
    qf[half] = *(const short8*)(Qf + (size_t)(b * 256 + g) * 1024 + half * 512 + lane * 8);

  const ushort_t* Kbase = Kf + (size_t)b * 256 * 1024;
  const ushort_t* Vbase = Vf + (size_t)b * 64 * 8 * 512;

  short8 ones;
#pragma unroll
  for (int e = 0; e < 8; ++e) ones[e] = (short)0x3F80;  // bf16 1.0

  floatx4 o[4], ol;
#pragma unroll
  for (int ht = 0; ht < 4; ++ht) { o[ht][0]=0.f; o[ht][1]=0.f; o[ht][2]=0.f; o[ht][3]=0.f; }
  ol[0]=0.f; ol[1]=0.f; ol[2]=0.f; ol[3]=0.f;

  const int ntile = (g >> 2) + 1;
  const int dtile = ntile - 1;

  for (int i = wv; i < ntile; i += 4) {
    // K and V for tile i (single-buffered; 4 waves/SIMD hide the latency)
    short8 kf[8], vf[8];
#pragma unroll
    for (int kt = 0; kt < 4; ++kt) {
      const ushort_t* kp = Kbase + (size_t)i * 4096 + kt * 1024 + lane * 8;
      kf[kt * 2]     = *(const short8*)(kp);
      kf[kt * 2 + 1] = *(const short8*)(kp + 512);
    }
#pragma unroll
    for (int ht = 0; ht < 4; ++ht) {
#pragma unroll
      for (int kh = 0; kh < 2; ++kh)
        vf[ht * 2 + kh] = *(const short8*)(Vbase + ((size_t)i * 8 + ht * 2 + kh) * 512 + lane * 8);
    }

    // S^T = K Q^T (swapped): lane(quad,col) reg r of s[kt] holds
    // S[key = 64i+16kt+4quad+r][q = g*16+col]
    floatx4 s[4];
    __builtin_amdgcn_s_setprio(1);
#pragma unroll
    for (int kt = 0; kt < 4; ++kt) {
      floatx4 c; c[0]=0.f; c[1]=0.f; c[2]=0.f; c[3]=0.f;
      c = __builtin_amdgcn_mfma_f32_16x16x32_bf16(kf[kt * 2],     qf[0], c, 0, 0, 0);
      c = __builtin_amdgcn_mfma_f32_16x16x32_bf16(kf[kt * 2 + 1], qf[1], c, 0, 0, 0);
      s[kt] = c;
    }
    __builtin_amdgcn_s_setprio(0);

    if (i == dtile) {   // causal mask on diagonal tile (exp2(-inf)=0)
#pragma unroll
      for (int kt = 0; kt < 4; ++kt)
#pragma unroll
        for (int r = 0; r < 4; ++r)
          if (64 * i + kt * 16 + quad * 4 + r > g * 16 + col)
            s[kt][r] = -INFINITY;
    }

#pragma unroll
    for (int kt = 0; kt < 4; ++kt)
#pragma unroll
      for (int r = 0; r < 4; ++r)
        s[kt][r] = __builtin_amdgcn_exp2f(s[kt][r]);

    // pack P to bf16 A-fragments IN REGISTERS (key order = pi2, V matches)
    short8 pf[2];
#pragma unroll
    for (int kh = 0; kh < 2; ++kh) {
      ushort_t tmp[8];
#pragma unroll
      for (int half = 0; half < 2; ++half)
#pragma unroll
        for (int r = 0; r < 4; ++r)
          tmp[half * 4 + r] = f2bf_hu(s[2 * kh + half][r]);
      pf[kh] = *(short8*)tmp;
    }

    // O += P V (V pre-permuted to pi2); l += P 1
    __builtin_amdgcn_s_setprio(1);
#pragma unroll
    for (int ht = 0; ht < 4; ++ht) {
      o[ht] = __builtin_amdgcn_mfma_f32_16x16x32_bf16(pf[0], vf[ht * 2],     o[ht], 0, 0, 0);
      o[ht] = __builtin_amdgcn_mfma_f32_16x16x32_bf16(pf[1], vf[ht * 2 + 1], o[ht], 0, 0, 0);
    }
    ol = __builtin_amdgcn_mfma_f32_16x16x32_bf16(pf[0], ones, ol, 0, 0, 0);
    ol = __builtin_amdgcn_mfma_f32_16x16x32_bf16(pf[1], ones, ol, 0, 0, 0);
    __builtin_amdgcn_s_setprio(0);
  }

  // ---- merge 4 waves' partials (plain sums; max-free) ----
#pragma unroll
  for (int ht = 0; ht < 4; ++ht)
#pragma unroll
    for (int r = 0; r < 4; ++r)
      Om[wv][quad * 4 + r][ht * 16 + col] = o[ht][r];
  if (col == 0) {
#pragma unroll
    for (int r = 0; r < 4; ++r) Ml[wv][quad * 4 + r] = ol[r];
  }
  __syncthreads();

  const int rr = tid >> 4, h4 = (tid & 15) * 4;
  {
    float L = (Ml[0][rr] + Ml[1][rr]) + (Ml[2][rr] + Ml[3][rr]);
    float4 a; a.x = 0.f; a.y = 0.f; a.z = 0.f; a.w = 0.f;
#pragma unroll
    for (int w = 0; w < 4; ++w) {
      float4 ov = *(const float4*)&Om[w][rr][h4];
      a.x += ov.x; a.y += ov.y; a.z += ov.z; a.w += ov.w;
    }
    float inv = 1.f / L;
    a.x *= inv; a.y *= inv; a.z *= inv; a.w *= inv;
    *(float4*)(out + (size_t)(b * Tn + g * 16 + rr) * Hn + h4) = a;
  }
}

extern "C" void kernel_launch(void* const* d_in, const int* in_sizes, int n_in,
                              void* d_out, int out_size, void* d_ws, size_t ws_size,
                              hipStream_t stream) {
  const float* x  = (const float*)d_in[0];
  const float* Wq = (const float*)d_in[1];
  const float* Wk = (const float*)d_in[2];
  const float* Wv = (const float*)d_in[3];
  float* out = (float*)d_out;

  ushort_t* Qf = (ushort_t*)d_ws;                   // 2 MB frag-major (pre-scaled)
  ushort_t* Kf = Qf + (size_t)Bn * Tn * Hn;         // 2 MB
  ushort_t* Vf = Kf + (size_t)Bn * Tn * Hn;         // 2 MB (pi2-permuted keys)
  ushort_t* Wf = Vf + (size_t)Bn * Tn * Hn;         // 384 KB

  wf_kernel<<<dim3(96), dim3(256), 0, stream>>>(Wq, Wk, Wv, Wf);
  qkv_proj_kernel<<<dim3(1024), dim3(256), 0, stream>>>(x, Wf, Qf, Kf, Vf);
  attn_kernel<<<dim3(Bn * 256), dim3(256), 0, stream>>>(Qf, Kf, Vf, out);
}

// Round 7
// 129.405 us; speedup vs baseline: 1.0101x; 1.0101x over previous
//
#include <hip/hip_runtime.h>
#include <math.h>

#define Bn 4
#define Tn 4096
#define Cn 1024
#define Hn 64

typedef __attribute__((ext_vector_type(8))) short short8;
typedef __attribute__((ext_vector_type(4))) float floatx4;
typedef unsigned short ushort_t;

// 0.125 (H^-0.5) * log2(e): folded into Q so attn uses native exp2
#define QSCALE 0.1803368801111204f

__device__ __forceinline__ ushort_t f2bf(float f) {       // RNE
  union { float f; unsigned u; } v; v.f = f;
  unsigned r = v.u + 0x7FFFu + ((v.u >> 16) & 1u);
  return (ushort_t)(r >> 16);
}
__device__ __forceinline__ ushort_t f2bf_hu(float f) {    // round-half-up (P only)
  union { float f; unsigned u; } v; v.f = f;
  return (ushort_t)((v.u + 0x8000u) >> 16);
}
__device__ __forceinline__ float bf2f(ushort_t h) {
  union { unsigned u; float f; } v; v.u = ((unsigned)h) << 16; return v.f;
}

// ---------------------------------------------------------------------------
// Layouts (lane = (quad=lane>>4, col=lane&15); addresses = base + lane*16B):
//  Qf/Kf[b][s=t/16][half=h/32]: lane holds h = half*32+quad*8+e for t=s*16+col.
//  Vf[b][i=t/64][ht=h/16][kh]: lane reg e holds V[t=i*64+pi2(kh,quad,e)][ht*16+col]
//    with pi2 = 32*kh + 16*(e>>2) + 4*quad + (e&3). Matches the SWAPPED-QK
//    register layout of P (S^T = mfma(K,Q): lane holds keys 16*kt+4*quad+r for
//    q=col), so P feeds PV's A-fragment directly from registers -- no LDS.
//  Wf[m][g=c/32][nt=h/16]: lane holds W[c=g*32+quad*8+e][h=nt*16+col].
// R7: cooperative fusion is DEAD (R6: launch silently fails under graph
// capture -> zeros). Back to 3 dispatches: R3's qkv (best measured, <40.4us)
// + R2's attn with tile-PAIR unroll: halves load-wait events per wave while
// keeping all load live-ranges WITHIN the iteration (R4's regression came
// from loop-carried prefetch ranges).
// ---------------------------------------------------------------------------

// W^T -> fragment-major bf16. grid = 96 (m*32+g), 256 threads.
__global__ __launch_bounds__(256) void wf_kernel(
    const float* __restrict__ Wq, const float* __restrict__ Wk,
    const float* __restrict__ Wv, ushort_t* __restrict__ Wf)
{
  __shared__ float ws[32][65];
  const int tid = threadIdx.x;
  const int m = blockIdx.x >> 5;
  const int g = blockIdx.x & 31;
  const float* W = (m == 0) ? Wq : (m == 1) ? Wk : Wv;
  const float4* src = (const float4*)(W + (size_t)g * 32 * Hn);
#pragma unroll
  for (int it = 0; it < 2; ++it) {
    int i4 = it * 256 + tid;
    float4 v = src[i4];
    int c = i4 >> 4, h = (i4 & 15) * 4;
    ws[c][h] = v.x; ws[c][h + 1] = v.y; ws[c][h + 2] = v.z; ws[c][h + 3] = v.w;
  }
  __syncthreads();
  const int nt = tid >> 6, lane = tid & 63;
  const int col = lane & 15, quad = lane >> 4;
  ushort_t t[8];
#pragma unroll
  for (int e = 0; e < 8; ++e) t[e] = f2bf(ws[quad * 8 + e][nt * 16 + col]);
  *(short8*)(Wf + ((size_t)((m * 32 + g) * 4 + nt) * 64 + lane) * 8) = *(short8*)t;
}

// ---------------------------------------------------------------------------
// QKV projection (R3 variant -- best measured: dropped below the 40.4us fill
// line vs R2's 44.7). grid = 512 x 256; block owns 32 rows (2 subtiles), 4
// waves K-split (256 ch each). Wf set0 issued FIRST, x staged 16-deep
// batched, ch-loop 2x-unrolled with A/B ping-pong (zero register copies).
// Epilogue: partials to LDS bf16 (STATIC acc indexing), per-wave reduce,
// frag-image staging, coalesced copy-out. 3 barriers/block.
// ---------------------------------------------------------------------------
__global__ __launch_bounds__(256, 2) void qkv_proj_kernel(
    const float* __restrict__ x, const ushort_t* __restrict__ Wf,
    ushort_t* __restrict__ Qf, ushort_t* __restrict__ Kf,
    ushort_t* __restrict__ Vf)
{
  __shared__ __align__(16) char smem[67584];
  ushort_t* xs  = (ushort_t*)smem;              // [4 wv][32 row][264] bf16 (67584 B)
  ushort_t* red = (ushort_t*)smem;              // overlays xs: [24][4][64][4] (49152 B)
  ushort_t* img = (ushort_t*)(smem + 49152);    // Q[2][1024] K[2][1024] V[4][512]

  const int tid  = threadIdx.x;
  const int wv   = tid >> 6;
  const int lane = tid & 63;
  const int col  = lane & 15;
  const int quad = lane >> 4;
  const int blk  = blockIdx.x;
  const int row0 = blk * 32;

#define BF_LOAD(DST, GG)                                                        \
  do {                                                                          \
    _Pragma("unroll")                                                           \
    for (int k = 0; k < 12; ++k) {                                              \
      const int m_ = k >> 2, nt_ = k & 3;                                       \
      DST[k] = *(const short8*)(Wf + ((size_t)((m_ * 32 + (GG)) * 4 + nt_) * 64 + lane) * 8); \
    }                                                                           \
  } while (0)

  // ---- issue first Wf fragment set BEFORE staging (independent streams) ----
  short8 bfA[12], bfB[12];
  BF_LOAD(bfA, wv * 8);

  // ---- stage wave's x slice (32 rows x 256 ch) to LDS, 16 loads in flight ----
#pragma unroll
  for (int half = 0; half < 2; ++half) {
    float4 v[16];
#pragma unroll
    for (int jj = 0; jj < 16; ++jj)
      v[jj] = *(const float4*)(x + (size_t)(row0 + half * 16 + jj) * Cn + wv * 256 + lane * 4);
#pragma unroll
    for (int jj = 0; jj < 16; ++jj) {
      ushort4 u;
      u.x = f2bf(v[jj].x); u.y = f2bf(v[jj].y); u.z = f2bf(v[jj].z); u.w = f2bf(v[jj].w);
      *(ushort4*)(xs + (wv * 32 + half * 16 + jj) * 264 + lane * 4) = u;
    }
  }
  // wave reads only its own slice -> no barrier (lgkmcnt orders same-wave LDS)

  floatx4 acc[2][3][4];
#pragma unroll
  for (int sub = 0; sub < 2; ++sub)
#pragma unroll
    for (int m = 0; m < 3; ++m)
#pragma unroll
      for (int nt = 0; nt < 4; ++nt) {
        acc[sub][m][nt][0] = 0.f; acc[sub][m][nt][1] = 0.f;
        acc[sub][m][nt][2] = 0.f; acc[sub][m][nt][3] = 0.f;
      }

#define QKV_MFMA(BF, CH)                                                        \
  do {                                                                          \
    short8 af0 = *(const short8*)(xs + (wv * 32 + col) * 264 + (CH) * 32 + quad * 8);        \
    short8 af1 = *(const short8*)(xs + (wv * 32 + 16 + col) * 264 + (CH) * 32 + quad * 8);   \
    _Pragma("unroll")                                                           \
    for (int k = 0; k < 12; ++k) {                                              \
      const int m_ = k >> 2, nt_ = k & 3;                                       \
      acc[0][m_][nt_] = __builtin_amdgcn_mfma_f32_16x16x32_bf16(af0, BF[k], acc[0][m_][nt_], 0, 0, 0); \
      acc[1][m_][nt_] = __builtin_amdgcn_mfma_f32_16x16x32_bf16(af1, BF[k], acc[1][m_][nt_], 0, 0, 0); \
    }                                                                           \
  } while (0)

  // ---- K-loop: 8 x 32ch, 2x-unrolled, A/B ping-pong (no copies) ----
#pragma unroll
  for (int ch2 = 0; ch2 < 4; ++ch2) {
    const int ch = ch2 * 2;
    BF_LOAD(bfB, wv * 8 + ch + 1);          // prefetch odd set
    QKV_MFMA(bfA, ch);
    if (ch2 < 3) BF_LOAD(bfA, wv * 8 + ch + 2);  // prefetch next even set
    QKV_MFMA(bfB, ch + 1);
  }
  __syncthreads();   // xs reads done everywhere; safe to overlay red

  // ---- dump ALL partials to LDS (static acc indices; lane-contiguous 8B) ----
#pragma unroll
  for (int sub = 0; sub < 2; ++sub)
#pragma unroll
    for (int m = 0; m < 3; ++m)
#pragma unroll
      for (int nt = 0; nt < 4; ++nt) {
        const int p = (sub * 3 + m) * 4 + nt;
        ushort4 u;
        u.x = f2bf(acc[sub][m][nt][0]); u.y = f2bf(acc[sub][m][nt][1]);
        u.z = f2bf(acc[sub][m][nt][2]); u.w = f2bf(acc[sub][m][nt][3]);
        *(ushort4*)&red[((p * 4 + wv) * 64 + lane) * 4] = u;
      }
  __syncthreads();

  // ---- wave wv reduces p in [6wv, 6wv+6) from LDS; writes frag-images ----
#pragma unroll
  for (int pp = 0; pp < 6; ++pp) {
    const int p = wv * 6 + pp;
    ushort4 w0 = *(const ushort4*)&red[((p * 4 + 0) * 64 + lane) * 4];
    ushort4 w1 = *(const ushort4*)&red[((p * 4 + 1) * 64 + lane) * 4];
    ushort4 w2 = *(const ushort4*)&red[((p * 4 + 2) * 64 + lane) * 4];
    ushort4 w3 = *(const ushort4*)&red[((p * 4 + 3) * 64 + lane) * 4];
    float v[4];
    v[0] = (bf2f(w0.x) + bf2f(w1.x)) + (bf2f(w2.x) + bf2f(w3.x));
    v[1] = (bf2f(w0.y) + bf2f(w1.y)) + (bf2f(w2.y) + bf2f(w3.y));
    v[2] = (bf2f(w0.z) + bf2f(w1.z)) + (bf2f(w2.z) + bf2f(w3.z));
    v[3] = (bf2f(w0.w) + bf2f(w1.w)) + (bf2f(w2.w) + bf2f(w3.w));
    const int sub = (p >= 12) ? 1 : 0;
    const int mrem = p - sub * 12;
    const int m = mrem >> 2, nt = mrem & 3;
#pragma unroll
    for (int r = 0; r < 4; ++r) {
      const int tlq = quad * 4 + r;
      if (m == 2) {
        // V image for swapped-QK attn: slot (quad, e=sub*4+r) holds local key
        // 16*sub + 4*quad + r  (pi2 with kh supplied by the copy-out's g&1)
        img[4096 + nt * 512 + (quad * 16 + col) * 8 + sub * 4 + r] = f2bf(v[r]);
      } else {
        const int h = nt * 16 + col;
        const int idx = (h >> 5) * 512 + ((h >> 3) & 3) * 128 + tlq * 8 + (h & 7);
        img[m * 2048 + sub * 1024 + idx] = f2bf(m == 0 ? v[r] * QSCALE : v[r]);
      }
    }
  }
  __syncthreads();

  // ---- coalesced copy-out ----
  {
    const int b = blk >> 7, g = blk & 127;
#pragma unroll
    for (int sub = 0; sub < 2; ++sub) {
      const size_t qg = (size_t)(b * 256 + 2 * g + sub) * 1024 + tid * 4;
      *(uint2*)(Qf + qg) = *(const uint2*)&img[sub * 1024 + tid * 4];
      *(uint2*)(Kf + qg) = *(const uint2*)&img[2048 + sub * 1024 + tid * 4];
    }
    const int ht = tid >> 6;
    const size_t vg = ((size_t)(b * 64 + (g >> 1)) * 8 + ht * 2 + (g & 1)) * 512 + (tid & 63) * 8;
    *(short8*)(Vf + vg) = *(const short8*)&img[4096 + ht * 512 + (tid & 63) * 8];
  }
}

// ---------------------------------------------------------------------------
// Flash attention, causal, max-free softmax. grid = B*128 (32-row q-tiles).
// g remap balances per-CU work. 4 waves take CONSECUTIVE TILE PAIRS (i0,i0+1),
// stride 8: all 32 K/V loads for both tiles issue together, then both bodies
// compute -> load-wait events per wave halve vs R2. Unlike R4's ping-pong,
// no load live-range crosses an iteration boundary. Body computes sub=0 then
// sub=1 sequentially to cap VGPR (~220 < 256). SWAPPED QK^T keeps P entirely
// in registers; zero barriers in the main loop.
// ---------------------------------------------------------------------------
__global__ __launch_bounds__(256, 2) void attn_kernel(
    const ushort_t* __restrict__ Qf, const ushort_t* __restrict__ Kf,
    const ushort_t* __restrict__ Vf, float* __restrict__ out)
{
  __shared__ __align__(16) float Om[4][2][16][68];
  __shared__ __align__(16) float Ml[4][2][16];

  const int tid  = threadIdx.x;
  const int wv   = tid >> 6;
  const int lane = tid & 63;
  const int col  = lane & 15;
  const int quad = lane >> 4;
  const int b   = blockIdx.x & 3;
  const int idx = blockIdx.x >> 2;                          // 0..127
  const int g   = (idx < 64) ? (127 - 2 * idx) : (2 * (idx - 64));  // balanced remap

  short8 qf[2][2];
#pragma unroll
  for (int sub = 0; sub < 2; ++sub)
#pragma unroll
    for (int half = 0; half < 2; ++half)
      qf[sub][half] = *(const short8*)(Qf + (size_t)(b * 256 + 2 * g + sub) * 1024 + half * 512 + lane * 8);

  const ushort_t* Kbase = Kf + (size_t)b * 256 * 1024;
  const ushort_t* Vbase = Vf + (size_t)b * 64 * 8 * 512;

  short8 ones;
#pragma unroll
  for (int e = 0; e < 8; ++e) ones[e] = (short)0x3F80;  // bf16 1.0

  floatx4 o[2][4], ol[2];
#pragma unroll
  for (int sub = 0; sub < 2; ++sub) {
#pragma unroll
    for (int ht = 0; ht < 4; ++ht) { o[sub][ht][0]=0.f; o[sub][ht][1]=0.f; o[sub][ht][2]=0.f; o[sub][ht][3]=0.f; }
    ol[sub][0]=0.f; ol[sub][1]=0.f; ol[sub][2]=0.f; ol[sub][3]=0.f;
  }

  const int ntile = ((g * 32 + 31) >> 6) + 1;
  const int dtile = ntile - 1;

#define LOADKV(KF, VF, II)                                                      \
  do {                                                                          \
    _Pragma("unroll")                                                           \
    for (int kt = 0; kt < 4; ++kt) {                                            \
      const ushort_t* kp = Kbase + (size_t)(II) * 4096 + kt * 1024 + lane * 8;  \
      KF[kt * 2]     = *(const short8*)(kp);                                    \
      KF[kt * 2 + 1] = *(const short8*)(kp + 512);                              \
    }                                                                           \
    _Pragma("unroll")                                                           \
    for (int ht = 0; ht < 4; ++ht) {                                            \
      _Pragma("unroll")                                                         \
      for (int kh = 0; kh < 2; ++kh)                                            \
        VF[ht * 2 + kh] = *(const short8*)(Vbase + ((size_t)(II) * 8 + ht * 2 + kh) * 512 + lane * 8); \
    }                                                                           \
  } while (0)

  // per-sub sequential body: s/pf live ranges stay short (VGPR cap)
#define TILE_BODY(KF, VF, II)                                                   \
  do {                                                                          \
    _Pragma("unroll")                                                           \
    for (int sub = 0; sub < 2; ++sub) {                                         \
      floatx4 s[4];                                                             \
      __builtin_amdgcn_s_setprio(1);                                            \
      _Pragma("unroll")                                                         \
      for (int kt = 0; kt < 4; ++kt) {                                          \
        floatx4 c; c[0]=0.f; c[1]=0.f; c[2]=0.f; c[3]=0.f;                      \
        c = __builtin_amdgcn_mfma_f32_16x16x32_bf16(KF[kt * 2],     qf[sub][0], c, 0, 0, 0); \
        c = __builtin_amdgcn_mfma_f32_16x16x32_bf16(KF[kt * 2 + 1], qf[sub][1], c, 0, 0, 0); \
        s[kt] = c;                                                              \
      }                                                                         \
      __builtin_amdgcn_s_setprio(0);                                            \
      if ((II) == dtile) {                                                      \
        _Pragma("unroll")                                                       \
        for (int kt = 0; kt < 4; ++kt)                                          \
          _Pragma("unroll")                                                     \
          for (int r = 0; r < 4; ++r)                                           \
            if (64 * (II) + kt * 16 + quad * 4 + r > g * 32 + sub * 16 + col)   \
              s[kt][r] = -INFINITY;                                             \
      }                                                                         \
      _Pragma("unroll")                                                         \
      for (int kt = 0; kt < 4; ++kt)                                            \
        _Pragma("unroll")                                                       \
        for (int r = 0; r < 4; ++r)                                             \
          s[kt][r] = __builtin_amdgcn_exp2f(s[kt][r]);                          \
      short8 pf[2];                                                             \
      _Pragma("unroll")                                                         \
      for (int kh = 0; kh < 2; ++kh) {                                          \
        ushort_t tmp[8];                                                        \
        _Pragma("unroll")                                                       \
        for (int half = 0; half < 2; ++half)                                    \
          _Pragma("unroll")                                                     \
          for (int r = 0; r < 4; ++r)                                           \
            tmp[half * 4 + r] = f2bf_hu(s[2 * kh + half][r]);                   \
        pf[kh] = *(short8*)tmp;                                                 \
      }                                                                         \
      __builtin_amdgcn_s_setprio(1);                                            \
      _Pragma("unroll")                                                         \
      for (int ht = 0; ht < 4; ++ht) {                                          \
        o[sub][ht] = __builtin_amdgcn_mfma_f32_16x16x32_bf16(pf[0], VF[ht * 2],     o[sub][ht], 0, 0, 0); \
        o[sub][ht] = __builtin_amdgcn_mfma_f32_16x16x32_bf16(pf[1], VF[ht * 2 + 1], o[sub][ht], 0, 0, 0); \
      }                                                                         \
      ol[sub] = __builtin_amdgcn_mfma_f32_16x16x32_bf16(pf[0], ones, ol[sub], 0, 0, 0); \
      ol[sub] = __builtin_amdgcn_mfma_f32_16x16x32_bf16(pf[1], ones, ol[sub], 0, 0, 0); \
      __builtin_amdgcn_s_setprio(0);                                            \
    }                                                                           \
  } while (0)

  // ---- main loop: consecutive tile pairs, all loads issued before compute ----
  for (int i0 = wv * 2; i0 < ntile; i0 += 8) {
    short8 kfa[8], vfa[8], kfb[8], vfb[8];
    const int i1 = i0 + 1;
    const bool h2 = (i1 < ntile);              // wave-uniform
    LOADKV(kfa, vfa, i0);
    if (h2) LOADKV(kfb, vfb, i1);
    TILE_BODY(kfa, vfa, i0);
    if (h2) TILE_BODY(kfb, vfb, i1);
  }

  // ---- merge 4 waves' partials (plain sums; max-free) ----
#pragma unroll
  for (int sub = 0; sub < 2; ++sub) {
#pragma unroll
    for (int ht = 0; ht < 4; ++ht)
#pragma unroll
      for (int r = 0; r < 4; ++r)
        Om[wv][sub][quad * 4 + r][ht * 16 + col] = o[sub][ht][r];
    if (col == 0) {
#pragma unroll
      for (int r = 0; r < 4; ++r) Ml[wv][sub][quad * 4 + r] = ol[sub][r];
    }
  }
  __syncthreads();

  const int rr = tid >> 4, h4 = (tid & 15) * 4;
#pragma unroll
  for (int sub = 0; sub < 2; ++sub) {
    float L = (Ml[0][sub][rr] + Ml[1][sub][rr]) + (Ml[2][sub][rr] + Ml[3][sub][rr]);
    float4 a; a.x = 0.f; a.y = 0.f; a.z = 0.f; a.w = 0.f;
#pragma unroll
    for (int w = 0; w < 4; ++w) {
      float4 ov = *(const float4*)&Om[w][sub][rr][h4];
      a.x += ov.x; a.y += ov.y; a.z += ov.z; a.w += ov.w;
    }
    float inv = 1.f / L;
    a.x *= inv; a.y *= inv; a.z *= inv; a.w *= inv;
    *(float4*)(out + (size_t)(b * Tn + g * 32 + sub * 16 + rr) * Hn + h4) = a;
  }
}

extern "C" void kernel_launch(void* const* d_in, const int* in_sizes, int n_in,
                              void* d_out, int out_size, void* d_ws, size_t ws_size,
                              hipStream_t stream) {
  const float* x  = (const float*)d_in[0];
  const float* Wq = (const float*)d_in[1];
  const float* Wk = (const float*)d_in[2];
  const float* Wv = (const float*)d_in[3];
  float* out = (float*)d_out;

  ushort_t* Qf = (ushort_t*)d_ws;                   // 2 MB frag-major (pre-scaled)
  ushort_t* Kf = Qf + (size_t)Bn * Tn * Hn;         // 2 MB
  ushort_t* Vf = Kf + (size_t)Bn * Tn * Hn;         // 2 MB (pi2-permuted keys)
  ushort_t* Wf = Vf + (size_t)Bn * Tn * Hn;         // 384 KB

  wf_kernel<<<dim3(96), dim3(256), 0, stream>>>(Wq, Wk, Wv, Wf);
  qkv_proj_kernel<<<dim3(512), dim3(256), 0, stream>>>(x, Wf, Qf, Kf, Vf);
  attn_kernel<<<dim3(Bn * 128), dim3(256), 0, stream>>>(Qf, Kf, Vf, out);
}

// Round 8
// 123.474 us; speedup vs baseline: 1.0586x; 1.0480x over previous
//
#include <hip/hip_runtime.h>
#include <math.h>

#define Bn 4
#define Tn 4096
#define Cn 1024
#define Hn 64

typedef __attribute__((ext_vector_type(8))) short short8;
typedef __attribute__((ext_vector_type(4))) float floatx4;
typedef unsigned short ushort_t;

// 0.125 (H^-0.5) * log2(e): folded into Q so attn uses native exp2
#define QSCALE 0.1803368801111204f

// Compiler fence: loads above cannot sink below, stores below cannot hoist
// above. Forces issued-load batches to stay batched (R7 evidence: without
// this, hipcc re-serializes every register-staging loop to minimal pressure
// -- VGPR_Count stayed 88 across R2/R3/R7 despite 96+ regs of declared
// staging buffers, and Little's law pinned qkv at ~900 GB/s in-flight-limited).
#define ILP_FENCE() asm volatile("" ::: "memory")

__device__ __forceinline__ ushort_t f2bf(float f) {       // RNE
  union { float f; unsigned u; } v; v.f = f;
  unsigned r = v.u + 0x7FFFu + ((v.u >> 16) & 1u);
  return (ushort_t)(r >> 16);
}
__device__ __forceinline__ ushort_t f2bf_hu(float f) {    // round-half-up (P only)
  union { float f; unsigned u; } v; v.f = f;
  return (ushort_t)((v.u + 0x8000u) >> 16);
}
__device__ __forceinline__ float bf2f(ushort_t h) {
  union { unsigned u; float f; } v; v.u = ((unsigned)h) << 16; return v.f;
}

// ---------------------------------------------------------------------------
// Layouts (lane = (quad=lane>>4, col=lane&15); addresses = base + lane*16B):
//  Qf/Kf[b][s=t/16][half=h/32]: lane holds h = half*32+quad*8+e for t=s*16+col.
//  Vf[b][i=t/64][ht=h/16][kh]: lane reg e holds V[t=i*64+pi2(kh,quad,e)][ht*16+col]
//    with pi2 = 32*kh + 16*(e>>2) + 4*quad + (e&3). Matches the SWAPPED-QK
//    register layout of P (S^T = mfma(K,Q): lane holds keys 16*kt+4*quad+r for
//    q=col), so P feeds PV's A-fragment directly from registers -- no LDS.
//  Wf[m][g=c/32][nt=h/16]: lane holds W[c=g*32+quad*8+e][h=nt*16+col].
// ---------------------------------------------------------------------------

// W^T -> fragment-major bf16. grid = 96 (m*32+g), 256 threads.
__global__ __launch_bounds__(256) void wf_kernel(
    const float* __restrict__ Wq, const float* __restrict__ Wk,
    const float* __restrict__ Wv, ushort_t* __restrict__ Wf)
{
  __shared__ float ws[32][65];
  const int tid = threadIdx.x;
  const int m = blockIdx.x >> 5;
  const int g = blockIdx.x & 31;
  const float* W = (m == 0) ? Wq : (m == 1) ? Wk : Wv;
  const float4* src = (const float4*)(W + (size_t)g * 32 * Hn);
#pragma unroll
  for (int it = 0; it < 2; ++it) {
    int i4 = it * 256 + tid;
    float4 v = src[i4];
    int c = i4 >> 4, h = (i4 & 15) * 4;
    ws[c][h] = v.x; ws[c][h + 1] = v.y; ws[c][h + 2] = v.z; ws[c][h + 3] = v.w;
  }
  __syncthreads();
  const int nt = tid >> 6, lane = tid & 63;
  const int col = lane & 15, quad = lane >> 4;
  ushort_t t[8];
#pragma unroll
  for (int e = 0; e < 8; ++e) t[e] = f2bf(ws[quad * 8 + e][nt * 16 + col]);
  *(short8*)(Wf + ((size_t)((m * 32 + g) * 4 + nt) * 64 + lane) * 8) = *(short8*)t;
}

// ---------------------------------------------------------------------------
// QKV projection. grid = 512 x 256; block owns 32 rows (2 subtiles), 4 waves
// K-split (256 ch each). R8: ILP_FENCE after each load batch -- staging in
// two 16-deep fenced batches (16KB/wave in flight vs ~4-8KB serialized);
// K-loop issues 12 Wf + 2 af loads per ch, fence, 24-MFMA cluster.
// Epilogue: partials to LDS bf16 (STATIC acc indexing), per-wave reduce,
// frag-image staging, coalesced copy-out. 3 barriers/block.
// ---------------------------------------------------------------------------
__global__ __launch_bounds__(256, 2) void qkv_proj_kernel(
    const float* __restrict__ x, const ushort_t* __restrict__ Wf,
    ushort_t* __restrict__ Qf, ushort_t* __restrict__ Kf,
    ushort_t* __restrict__ Vf)
{
  __shared__ __align__(16) char smem[67584];
  ushort_t* xs  = (ushort_t*)smem;              // [4 wv][32 row][264] bf16 (67584 B)
  ushort_t* red = (ushort_t*)smem;              // overlays xs: [24][4][64][4] (49152 B)
  ushort_t* img = (ushort_t*)(smem + 49152);    // Q[2][1024] K[2][1024] V[4][512]

  const int tid  = threadIdx.x;
  const int wv   = tid >> 6;
  const int lane = tid & 63;
  const int col  = lane & 15;
  const int quad = lane >> 4;
  const int blk  = blockIdx.x;
  const int row0 = blk * 32;

  // ---- stage wave's x slice (32 rows x 256 ch): 2 fenced 16-load batches ----
#pragma unroll
  for (int half = 0; half < 2; ++half) {
    float4 v[16];
#pragma unroll
    for (int jj = 0; jj < 16; ++jj)
      v[jj] = *(const float4*)(x + (size_t)(row0 + half * 16 + jj) * Cn + wv * 256 + lane * 4);
    ILP_FENCE();   // all 16 loads issued & live before any LDS store
#pragma unroll
    for (int jj = 0; jj < 16; ++jj) {
      ushort4 u;
      u.x = f2bf(v[jj].x); u.y = f2bf(v[jj].y); u.z = f2bf(v[jj].z); u.w = f2bf(v[jj].w);
      *(ushort4*)(xs + (wv * 32 + half * 16 + jj) * 264 + lane * 4) = u;
    }
  }
  // wave reads only its own slice -> no barrier (lgkmcnt orders same-wave LDS)

  floatx4 acc[2][3][4];
#pragma unroll
  for (int sub = 0; sub < 2; ++sub)
#pragma unroll
    for (int m = 0; m < 3; ++m)
#pragma unroll
      for (int nt = 0; nt < 4; ++nt) {
        acc[sub][m][nt][0] = 0.f; acc[sub][m][nt][1] = 0.f;
        acc[sub][m][nt][2] = 0.f; acc[sub][m][nt][3] = 0.f;
      }

  // ---- K-loop: 8 x 32ch; fenced 12-load Wf batch + af, then MFMA cluster ----
#pragma unroll
  for (int ch = 0; ch < 8; ++ch) {
    const int gg = wv * 8 + ch;                 // global 32-ch chunk
    short8 bf[12];
#pragma unroll
    for (int k = 0; k < 12; ++k) {
      const int m_ = k >> 2, nt_ = k & 3;
      bf[k] = *(const short8*)(Wf + ((size_t)((m_ * 32 + gg) * 4 + nt_) * 64 + lane) * 8);
    }
    short8 af0 = *(const short8*)(xs + (wv * 32 + col) * 264 + ch * 32 + quad * 8);
    short8 af1 = *(const short8*)(xs + (wv * 32 + 16 + col) * 264 + ch * 32 + quad * 8);
    ILP_FENCE();   // 12 global + 2 LDS loads all in flight before compute
#pragma unroll
    for (int k = 0; k < 12; ++k) {
      const int m_ = k >> 2, nt_ = k & 3;
      acc[0][m_][nt_] = __builtin_amdgcn_mfma_f32_16x16x32_bf16(af0, bf[k], acc[0][m_][nt_], 0, 0, 0);
      acc[1][m_][nt_] = __builtin_amdgcn_mfma_f32_16x16x32_bf16(af1, bf[k], acc[1][m_][nt_], 0, 0, 0);
    }
  }
  __syncthreads();   // xs reads done everywhere; safe to overlay red

  // ---- dump ALL partials to LDS (static acc indices; lane-contiguous 8B) ----
#pragma unroll
  for (int sub = 0; sub < 2; ++sub)
#pragma unroll
    for (int m = 0; m < 3; ++m)
#pragma unroll
      for (int nt = 0; nt < 4; ++nt) {
        const int p = (sub * 3 + m) * 4 + nt;
        ushort4 u;
        u.x = f2bf(acc[sub][m][nt][0]); u.y = f2bf(acc[sub][m][nt][1]);
        u.z = f2bf(acc[sub][m][nt][2]); u.w = f2bf(acc[sub][m][nt][3]);
        *(ushort4*)&red[((p * 4 + wv) * 64 + lane) * 4] = u;
      }
  __syncthreads();

  // ---- wave wv reduces p in [6wv, 6wv+6) from LDS; writes frag-images ----
#pragma unroll
  for (int pp = 0; pp < 6; ++pp) {
    const int p = wv * 6 + pp;
    ushort4 w0 = *(const ushort4*)&red[((p * 4 + 0) * 64 + lane) * 4];
    ushort4 w1 = *(const ushort4*)&red[((p * 4 + 1) * 64 + lane) * 4];
    ushort4 w2 = *(const ushort4*)&red[((p * 4 + 2) * 64 + lane) * 4];
    ushort4 w3 = *(const ushort4*)&red[((p * 4 + 3) * 64 + lane) * 4];
    float v[4];
    v[0] = (bf2f(w0.x) + bf2f(w1.x)) + (bf2f(w2.x) + bf2f(w3.x));
    v[1] = (bf2f(w0.y) + bf2f(w1.y)) + (bf2f(w2.y) + bf2f(w3.y));
    v[2] = (bf2f(w0.z) + bf2f(w1.z)) + (bf2f(w2.z) + bf2f(w3.z));
    v[3] = (bf2f(w0.w) + bf2f(w1.w)) + (bf2f(w2.w) + bf2f(w3.w));
    const int sub = (p >= 12) ? 1 : 0;
    const int mrem = p - sub * 12;
    const int m = mrem >> 2, nt = mrem & 3;
#pragma unroll
    for (int r = 0; r < 4; ++r) {
      const int tlq = quad * 4 + r;
      if (m == 2) {
        // V image for swapped-QK attn: slot (quad, e=sub*4+r) holds local key
        // 16*sub + 4*quad + r  (pi2 with kh supplied by the copy-out's g&1)
        img[4096 + nt * 512 + (quad * 16 + col) * 8 + sub * 4 + r] = f2bf(v[r]);
      } else {
        const int h = nt * 16 + col;
        const int idx = (h >> 5) * 512 + ((h >> 3) & 3) * 128 + tlq * 8 + (h & 7);
        img[m * 2048 + sub * 1024 + idx] = f2bf(m == 0 ? v[r] * QSCALE : v[r]);
      }
    }
  }
  __syncthreads();

  // ---- coalesced copy-out ----
  {
    const int b = blk >> 7, g = blk & 127;
#pragma unroll
    for (int sub = 0; sub < 2; ++sub) {
      const size_t qg = (size_t)(b * 256 + 2 * g + sub) * 1024 + tid * 4;
      *(uint2*)(Qf + qg) = *(const uint2*)&img[sub * 1024 + tid * 4];
      *(uint2*)(Kf + qg) = *(const uint2*)&img[2048 + sub * 1024 + tid * 4];
    }
    const int ht = tid >> 6;
    const size_t vg = ((size_t)(b * 64 + (g >> 1)) * 8 + ht * 2 + (g & 1)) * 512 + (tid & 63) * 8;
    *(short8*)(Vf + vg) = *(const short8*)&img[4096 + ht * 512 + (tid & 63) * 8];
  }
}

// ---------------------------------------------------------------------------
// Flash attention, causal, max-free softmax. grid = B*128 (32-row q-tiles).
// g remap balances per-CU work. 4 waves stride 64-key tiles with private
// (O,l). SWAPPED QK^T keeps P entirely in registers; zero barriers in the
// main loop. R8: all 16 K/V loads of the tile issued as ONE fenced batch
// (4KB/wave in flight, one latency wait per tile instead of a serialized
// chain). No cross-tile prefetch (R4/R7: loop-carried or doubled batches
// regressed via pressure/serialization).
// ---------------------------------------------------------------------------
__global__ __launch_bounds__(256, 2) void attn_kernel(
    const ushort_t* __restrict__ Qf, const ushort_t* __restrict__ Kf,
    const ushort_t* __restrict__ Vf, float* __restrict__ out)
{
  __shared__ __align__(16) float Om[4][2][16][68];
  __shared__ __align__(16) float Ml[4][2][16];

  const int tid  = threadIdx.x;
  const int wv   = tid >> 6;
  const int lane = tid & 63;
  const int col  = lane & 15;
  const int quad = lane >> 4;
  const int b   = blockIdx.x & 3;
  const int idx = blockIdx.x >> 2;                          // 0..127
  const int g   = (idx < 64) ? (127 - 2 * idx) : (2 * (idx - 64));  // balanced remap

  short8 qf[2][2];
#pragma unroll
  for (int sub = 0; sub < 2; ++sub)
#pragma unroll
    for (int half = 0; half < 2; ++half)
      qf[sub][half] = *(const short8*)(Qf + (size_t)(b * 256 + 2 * g + sub) * 1024 + half * 512 + lane * 8);

  const ushort_t* Kbase = Kf + (size_t)b * 256 * 1024;
  const ushort_t* Vbase = Vf + (size_t)b * 64 * 8 * 512;

  short8 ones;
#pragma unroll
  for (int e = 0; e < 8; ++e) ones[e] = (short)0x3F80;  // bf16 1.0

  floatx4 o[2][4], ol[2];
#pragma unroll
  for (int sub = 0; sub < 2; ++sub) {
#pragma unroll
    for (int ht = 0; ht < 4; ++ht) { o[sub][ht][0]=0.f; o[sub][ht][1]=0.f; o[sub][ht][2]=0.f; o[sub][ht][3]=0.f; }
    ol[sub][0]=0.f; ol[sub][1]=0.f; ol[sub][2]=0.f; ol[sub][3]=0.f;
  }

  const int ntile = ((g * 32 + 31) >> 6) + 1;
  const int dtile = ntile - 1;

  for (int i = wv; i < ntile; i += 4) {
    // ---- one fenced batch: all 8 K + 8 V fragments of tile i in flight ----
    short8 kf[8], vf[8];
#pragma unroll
    for (int kt = 0; kt < 4; ++kt) {
      const ushort_t* kp = Kbase + (size_t)i * 4096 + kt * 1024 + lane * 8;
      kf[kt * 2]     = *(const short8*)(kp);
      kf[kt * 2 + 1] = *(const short8*)(kp + 512);
    }
#pragma unroll
    for (int ht = 0; ht < 4; ++ht) {
#pragma unroll
      for (int kh = 0; kh < 2; ++kh)
        vf[ht * 2 + kh] = *(const short8*)(Vbase + ((size_t)i * 8 + ht * 2 + kh) * 512 + lane * 8);
    }
    ILP_FENCE();

    // S^T = K Q^T (swapped): lane(quad,col) reg r of s[sub][kt] holds
    // S[key = 64i+16kt+4quad+r][q = g*32+sub*16+col]
    floatx4 s[2][4];
    __builtin_amdgcn_s_setprio(1);
#pragma unroll
    for (int sub = 0; sub < 2; ++sub)
#pragma unroll
      for (int kt = 0; kt < 4; ++kt) {
        floatx4 c; c[0]=0.f; c[1]=0.f; c[2]=0.f; c[3]=0.f;
        c = __builtin_amdgcn_mfma_f32_16x16x32_bf16(kf[kt * 2],     qf[sub][0], c, 0, 0, 0);
        c = __builtin_amdgcn_mfma_f32_16x16x32_bf16(kf[kt * 2 + 1], qf[sub][1], c, 0, 0, 0);
        s[sub][kt] = c;
      }
    __builtin_amdgcn_s_setprio(0);

    if (i == dtile) {   // causal mask on diagonal tile (exp2(-inf)=0)
#pragma unroll
      for (int sub = 0; sub < 2; ++sub)
#pragma unroll
        for (int kt = 0; kt < 4; ++kt)
#pragma unroll
          for (int r = 0; r < 4; ++r)
            if (64 * i + kt * 16 + quad * 4 + r > g * 32 + sub * 16 + col)
              s[sub][kt][r] = -INFINITY;
    }

#pragma unroll
    for (int sub = 0; sub < 2; ++sub)
#pragma unroll
      for (int kt = 0; kt < 4; ++kt)
#pragma unroll
        for (int r = 0; r < 4; ++r)
          s[sub][kt][r] = __builtin_amdgcn_exp2f(s[sub][kt][r]);

    // pack P to bf16 A-fragments IN REGISTERS (key order = pi2, V matches)
    short8 pf[2][2];
#pragma unroll
    for (int sub = 0; sub < 2; ++sub)
#pragma unroll
      for (int kh = 0; kh < 2; ++kh) {
        ushort_t tmp[8];
#pragma unroll
        for (int half = 0; half < 2; ++half)
#pragma unroll
          for (int r = 0; r < 4; ++r)
            tmp[half * 4 + r] = f2bf_hu(s[sub][2 * kh + half][r]);
        pf[sub][kh] = *(short8*)tmp;
      }

    // O += P V (V pre-permuted to pi2); l += P 1
    __builtin_amdgcn_s_setprio(1);
#pragma unroll
    for (int sub = 0; sub < 2; ++sub) {
#pragma unroll
      for (int ht = 0; ht < 4; ++ht) {
        o[sub][ht] = __builtin_amdgcn_mfma_f32_16x16x32_bf16(pf[sub][0], vf[ht * 2],     o[sub][ht], 0, 0, 0);
        o[sub][ht] = __builtin_amdgcn_mfma_f32_16x16x32_bf16(pf[sub][1], vf[ht * 2 + 1], o[sub][ht], 0, 0, 0);
      }
      ol[sub] = __builtin_amdgcn_mfma_f32_16x16x32_bf16(pf[sub][0], ones, ol[sub], 0, 0, 0);
      ol[sub] = __builtin_amdgcn_mfma_f32_16x16x32_bf16(pf[sub][1], ones, ol[sub], 0, 0, 0);
    }
    __builtin_amdgcn_s_setprio(0);
  }

  // ---- merge 4 waves' partials (plain sums; max-free) ----
#pragma unroll
  for (int sub = 0; sub < 2; ++sub) {
#pragma unroll
    for (int ht = 0; ht < 4; ++ht)
#pragma unroll
      for (int r = 0; r < 4; ++r)
        Om[wv][sub][quad * 4 + r][ht * 16 + col] = o[sub][ht][r];
    if (col == 0) {
#pragma unroll
      for (int r = 0; r < 4; ++r) Ml[wv][sub][quad * 4 + r] = ol[sub][r];
    }
  }
  __syncthreads();

  const int rr = tid >> 4, h4 = (tid & 15) * 4;
#pragma unroll
  for (int sub = 0; sub < 2; ++sub) {
    float L = (Ml[0][sub][rr] + Ml[1][sub][rr]) + (Ml[2][sub][rr] + Ml[3][sub][rr]);
    float4 a; a.x = 0.f; a.y = 0.f; a.z = 0.f; a.w = 0.f;
#pragma unroll
    for (int w = 0; w < 4; ++w) {
      float4 ov = *(const float4*)&Om[w][sub][rr][h4];
      a.x += ov.x; a.y += ov.y; a.z += ov.z; a.w += ov.w;
    }
    float inv = 1.f / L;
    a.x *= inv; a.y *= inv; a.z *= inv; a.w *= inv;
    *(float4*)(out + (size_t)(b * Tn + g * 32 + sub * 16 + rr) * Hn + h4) = a;
  }
}

extern "C" void kernel_launch(void* const* d_in, const int* in_sizes, int n_in,
                              void* d_out, int out_size, void* d_ws, size_t ws_size,
                              hipStream_t stream) {
  const float* x  = (const float*)d_in[0];
  const float* Wq = (const float*)d_in[1];
  const float* Wk = (const float*)d_in[2];
  const float* Wv = (const float*)d_in[3];
  float* out = (float*)d_out;

  ushort_t* Qf = (ushort_t*)d_ws;                   // 2 MB frag-major (pre-scaled)
  ushort_t* Kf = Qf + (size_t)Bn * Tn * Hn;         // 2 MB
  ushort_t* Vf = Kf + (size_t)Bn * Tn * Hn;         // 2 MB (pi2-permuted keys)
  ushort_t* Wf = Vf + (size_t)Bn * Tn * Hn;         // 384 KB

  wf_kernel<<<dim3(96), dim3(256), 0, stream>>>(Wq, Wk, Wv, Wf);
  qkv_proj_kernel<<<dim3(512), dim3(256), 0, stream>>>(x, Wf, Qf, Kf, Vf);
  attn_kernel<<<dim3(Bn * 128), dim3(256), 0, stream>>>(Qf, Kf, Vf, out);
}